// Round 3
// baseline (258.812 us; speedup 1.0000x reference)
//
#include <hip/hip_runtime.h>
#include <hip/hip_bf16.h>

// Problem constants
#define NN    16      // batch
#define INC   32
#define INN   65536
#define OUTC  32
#define OUTN  8192
#define MAXD  16
#define NC    512     // NN*INC

typedef __attribute__((ext_vector_type(8))) unsigned short ushort8;
typedef __attribute__((ext_vector_type(4))) float f32x4;

// ---------------------------------------------------------------------------
// Kernel A: feat[j][r] = x[r][j] * weight[r&31][j], stored bf16 (as ushort).
// x is (512, 65536) row-major; feat is (65536, 512) row-major in d_ws.
// 64(j) x 64(r) tile. LDS [j][r] stride 65 (2-way conflicts only = free).
// x read nontemporal (streamed once; preserve cache capacity for feat).
// ---------------------------------------------------------------------------
__global__ __launch_bounds__(256) void transpose_scale_kernel(
    const float* __restrict__ x,
    const float* __restrict__ weight,
    unsigned short* __restrict__ feat)
{
    __shared__ float tile[64][65];       // [j][r]
    const int l  = threadIdx.x;          // 0..255
    const int j0 = blockIdx.x * 64;      // 1024 blocks
    const int r0 = blockIdx.y * 64;      // 8 blocks

    #pragma unroll
    for (int it = 0; it < 4; ++it) {
        int idx = it * 256 + l;          // 0..1023
        int rl  = idx >> 4;              // 0..63
        int jj  = idx & 15;              // float4 group along j
        int r   = r0 + rl;
        int c   = r & 31;
        int j   = j0 + jj * 4;
        f32x4 xv = __builtin_nontemporal_load(
            reinterpret_cast<const f32x4*>(x + (size_t)r * INN + j));
        f32x4 wv = *reinterpret_cast<const f32x4*>(weight + (size_t)c * INN + j);
        tile[jj * 4 + 0][rl] = xv[0] * wv[0];
        tile[jj * 4 + 1][rl] = xv[1] * wv[1];
        tile[jj * 4 + 2][rl] = xv[2] * wv[2];
        tile[jj * 4 + 3][rl] = xv[3] * wv[3];
    }
    __syncthreads();

    #pragma unroll
    for (int p = 0; p < 2; ++p) {
        int jl = p * 32 + (l >> 3);      // 0..63
        int rs = (l & 7) * 8;            // 0..56
        ushort8 pk;
        #pragma unroll
        for (int k = 0; k < 8; ++k) {
            float v = tile[jl][rs + k];
            pk[k] = __bfloat16_as_ushort(__float2bfloat16(v));
        }
        *reinterpret_cast<ushort8*>(
            feat + (size_t)(j0 + jl) * NC + r0 + rs) = pk;
    }
}

// ---------------------------------------------------------------------------
// Kernel B: 512 blocks x 512 threads; block owns OTILE=16 output nodes.
// Stage A/w/bias in LDS (kills the 3x wave-uniform VMEM overhead).
// Gather: wave w handles o = w, w+8; 1KB feat row per load instr.
// pooled stored SWIZZLED so b128 stores are lane-stride-16B (conflict-free);
// GEMM reads are broadcast so the permutation is free there.
//   storage: c = lane*8 + half*4 + t  ->  s = half*256 + lane*4 + t
// ---------------------------------------------------------------------------
#define OTILE 16

__global__ __launch_bounds__(512, 4) void gather_gemm_kernel(
    const unsigned short* __restrict__ feat,
    const int*   __restrict__ A,
    const float* __restrict__ mask,
    const float* __restrict__ mw,
    const float* __restrict__ ctw,
    const float* __restrict__ ctb,
    const float* __restrict__ bias,
    float*       __restrict__ out)
{
    __shared__ float pooled[OTILE][NC];      // 32 KB, swizzled columns
    __shared__ int   A_l[OTILE * MAXD];      // 1 KB
    __shared__ float w_l[OTILE * MAXD];      // 1 KB
    __shared__ float bias_l[32 * OTILE];     // 2 KB, [dout][o]

    const int l    = threadIdx.x;            // 0..511
    const int wave = l >> 6;                 // 0..7
    const int lane = l & 63;
    const int o0   = blockIdx.x * OTILE;     // 512 blocks

    if (l < OTILE * MAXD) {
        A_l[l] = A[o0 * MAXD + l] & (INN - 1);
        w_l[l] = mw[o0 * MAXD + l] * mask[o0 * MAXD + l];
    }
    {   // bias_l[dout*16 + o]
        int dout = l >> 4, o = l & 15;
        bias_l[l] = bias[(size_t)dout * OUTN + o0 + o];
    }
    __syncthreads();

    // Gather phase: 2 o's per wave.
    #pragma unroll
    for (int i = 0; i < 2; ++i) {
        const int o = wave + 8 * i;
        float acc[8] = {0.f, 0.f, 0.f, 0.f, 0.f, 0.f, 0.f, 0.f};
        #pragma unroll
        for (int d = 0; d < MAXD; ++d) {
            int   j  = A_l[o * MAXD + d];    // LDS broadcast
            float wv = w_l[o * MAXD + d];    // LDS broadcast
            ushort8 p = *reinterpret_cast<const ushort8*>(
                feat + (size_t)j * NC + lane * 8);
            #pragma unroll
            for (int k = 0; k < 8; ++k)
                acc[k] += wv * __uint_as_float((unsigned)p[k] << 16);
        }
        // swizzled b128 stores, lane-stride 16B -> conflict-free
        *reinterpret_cast<f32x4*>(&pooled[o][lane * 4]) =
            f32x4{acc[0], acc[1], acc[2], acc[3]};
        *reinterpret_cast<f32x4*>(&pooled[o][256 + lane * 4]) =
            f32x4{acc[4], acc[5], acc[6], acc[7]};
    }
    __syncthreads();

    // GEMM phase: thread l -> (n = l>>5, dout = l&31), all 16 o's.
    const int dout = l & 31;
    const int n    = l >> 5;
    const float cb = ctb[dout];
    float vals[OTILE];
    #pragma unroll
    for (int o = 0; o < OTILE; ++o) vals[o] = cb + bias_l[dout * OTILE + o];

    #pragma unroll
    for (int q = 0; q < 8; ++q) {            // q-outer: 8 ct float4 loads (L2-hit)
        f32x4 cw = *reinterpret_cast<const f32x4*>(ctw + dout * 32 + 4 * q);
        const int sbase = (q & 1) * 256 + n * 16 + 4 * (q >> 1);
        #pragma unroll
        for (int o = 0; o < OTILE; ++o) {
            f32x4 pv = *reinterpret_cast<const f32x4*>(&pooled[o][sbase]); // broadcast
            vals[o] += pv[0] * cw[0] + pv[1] * cw[1] + pv[2] * cw[2] + pv[3] * cw[3];
        }
    }

    float* orow = out + ((size_t)(n * 32 + dout)) * OUTN + o0;
    #pragma unroll
    for (int qq = 0; qq < 4; ++qq) {
        __builtin_nontemporal_store(
            f32x4{vals[4*qq], vals[4*qq+1], vals[4*qq+2], vals[4*qq+3]},
            reinterpret_cast<f32x4*>(orow + 4 * qq));
    }
}

extern "C" void kernel_launch(void* const* d_in, const int* in_sizes, int n_in,
                              void* d_out, int out_size, void* d_ws, size_t ws_size,
                              hipStream_t stream)
{
    const float* x      = (const float*)d_in[0];   // (16,32,65536)
    const int*   A      = (const int*)  d_in[1];   // (8192,16)
    const float* weight = (const float*)d_in[2];   // (32,65536)
    const float* mask   = (const float*)d_in[3];   // (8192,16,1)
    const float* mw     = (const float*)d_in[4];   // (8192,16,1)
    const float* ctw    = (const float*)d_in[5];   // (32,32)
    const float* ctb    = (const float*)d_in[6];   // (32,)
    const float* bias   = (const float*)d_in[7];   // (32,8192)
    float* out = (float*)d_out;                    // (16,32,8192)

    unsigned short* feat = (unsigned short*)d_ws;  // (65536, 512) bf16 = 67 MB

    dim3 gA(INN / 64, NC / 64);                    // 1024 x 8
    transpose_scale_kernel<<<gA, 256, 0, stream>>>(x, weight, feat);

    gather_gemm_kernel<<<OUTN / OTILE, 512, 0, stream>>>(
        feat, A, mask, mw, ctw, ctb, bias, out);
}